// Round 10
// baseline (126.759 us; speedup 1.0000x reference)
//
#include <hip/hip_runtime.h>

#define NDIM 2048
#define FDIM 64
#define KDIM 8
#define BDIM 32
#define TILE 64
#define BFROW 72   // bf16 elems per panel row (64 + 8 pad)
#define FROW  68   // f32 elems per transpose-panel row (64 + 4 pad)

typedef __attribute__((ext_vector_type(8))) short short8;
typedef __attribute__((ext_vector_type(4))) float f32x4;

static __device__ __forceinline__ unsigned short f2bf(float x) {
    unsigned u = __float_as_uint(x);                 // RNE to bf16
    return (unsigned short)((u + 0x7fffu + ((u >> 16) & 1u)) >> 16);
}

// ---------------------------------------------------------------------------
// R10 = R8 (last PASS, 125.6us) with two scheduling-only changes; all index
// formulas byte-identical to R8:
//  (1) cov phase double-buffered: stage L_{k+1} into the other bf16 panel
//      pair while MFMA-ing k -> 1 barrier/k instead of 2, latency hidden.
//  (2) epilogue ping-pong: scatter next plane-pair into P2/P3 in the same
//      barrier interval as read+store of current pair from P0/P1 -> mix FMA
//      issue overlaps store issue. Barriers stay lgkmcnt-only (stores are
//      never drained; LDS ordering fully covered).
// acc is consumed ONLY via the R5/R8-proven mix->scatter->LDS->read->store
// path (R6/R7/R9's register-reorg epilogues all failed ~absmax 20).
// ---------------------------------------------------------------------------
__global__ __launch_bounds__(256, 2) void rfm_fused_mfma(
    const float* __restrict__ p, const float* __restrict__ L,
    const float* __restrict__ sr, float* __restrict__ out)
{
    __shared__ float pl[BDIM * KDIM];
    __shared__ __align__(16) char smem[4 * TILE * FROW * 4];   // 69632 B

    // cov view: two double-buffered bf16 panel pairs (36864 B of the union)
    unsigned short* const An0 = (unsigned short*)smem;
    unsigned short* const Am0 = An0 + TILE * BFROW;
    unsigned short* const An1 = Am0 + TILE * BFROW;
    unsigned short* const Am1 = An1 + TILE * BFROW;
    // epilogue view: four f32 transpose panels
    float* const P0 = (float*)smem;
    float* const P1 = (float*)(smem + 1 * TILE * FROW * 4);
    float* const P2 = (float*)(smem + 2 * TILE * FROW * 4);
    float* const P3 = (float*)(smem + 3 * TILE * FROW * 4);

    const int n0 = blockIdx.y * TILE;
    const int m0 = blockIdx.x * TILE;
    const int t  = threadIdx.x;
    const int lane = t & 63;
    const int w   = t >> 6;        // wave 0..3
    const int wr  = w >> 1;        // row 32-block (n side)
    const int wc  = w & 1;         // col 32-block (m side)
    const int l15 = lane & 15;
    const int l4  = lane >> 4;     // 0..3

    pl[t] = p[t];                  // ordered before epilogue reads by barriers

    // staging helper (formula verbatim R8)
    auto STAGE = [&](int k, unsigned short* A, unsigned short* B) {
        const float* Lk = L + (size_t)k * (NDIM * FDIM);
        #pragma unroll
        for (int r = 0; r < 4; ++r) {
            const int idx = t + r * 256;
            const int row = idx >> 4;          // 16 float4 per row
            const int fc  = (idx & 15) << 2;
            const float4 va = *(const float4*)&Lk[(size_t)(n0 + row) * FDIM + fc];
            const float4 vb = *(const float4*)&Lk[(size_t)(m0 + row) * FDIM + fc];
            ushort4 ua, ub;
            ua.x = f2bf(va.x); ua.y = f2bf(va.y); ua.z = f2bf(va.z); ua.w = f2bf(va.w);
            ub.x = f2bf(vb.x); ub.y = f2bf(vb.y); ub.z = f2bf(vb.z); ub.w = f2bf(vb.w);
            *(ushort4*)&A[row * BFROW + fc] = ua;
            *(ushort4*)&B[row * BFROW + fc] = ub;
        }
    };

    f32x4 acc[KDIM][2][2];
    #pragma unroll
    for (int k = 0; k < KDIM; ++k)
        #pragma unroll
        for (int ti = 0; ti < 2; ++ti)
            #pragma unroll
            for (int tj = 0; tj < 2; ++tj)
                acc[k][ti][tj] = (f32x4){0.f, 0.f, 0.f, 0.f};

    // ---- 1) cov phase: double-buffered staging + MFMA (1 barrier per k) ----
    STAGE(0, An0, Am0);
    __syncthreads();
    #pragma unroll
    for (int k = 0; k < KDIM; ++k) {
        if (k + 1 < KDIM)                       // stage next k into other buf
            STAGE(k + 1, (k & 1) ? An0 : An1, (k & 1) ? Am0 : Am1);

        const unsigned short* Ac = (k & 1) ? An1 : An0;
        const unsigned short* Bc = (k & 1) ? Am1 : Am0;
        short8 af[2][2], bv[2][2];
        #pragma unroll
        for (int ti = 0; ti < 2; ++ti)
            #pragma unroll
            for (int s = 0; s < 2; ++s) {
                af[ti][s] = *(const short8*)
                    &Ac[(wr * 32 + ti * 16 + l15) * BFROW + s * 32 + l4 * 8];
                bv[ti][s] = *(const short8*)
                    &Bc[(wc * 32 + ti * 16 + l15) * BFROW + s * 32 + l4 * 8];
            }
        #pragma unroll
        for (int ti = 0; ti < 2; ++ti)
            #pragma unroll
            for (int tj = 0; tj < 2; ++tj)
                #pragma unroll
                for (int s = 0; s < 2; ++s)
                    acc[k][ti][tj] = __builtin_amdgcn_mfma_f32_16x16x32_bf16(
                        af[ti][s], bv[tj][s], acc[k][ti][tj], 0, 0, 0);
        __syncthreads();   // next-buf writes visible; current-buf reads done
    }

    // Diagonal (verbatim R8): C/D map row = l4*4 + reg, col = l15.
    if (n0 == m0 && wr == wc) {
        #pragma unroll
        for (int k = 0; k < KDIM; ++k)
            #pragma unroll
            for (int ti = 0; ti < 2; ++ti)
                #pragma unroll
                for (int reg = 0; reg < 4; ++reg) {
                    const int row = l4 * 4 + reg;
                    if (row == l15) {
                        const float q = sr[k * NDIM + n0 + wr * 32 + ti * 16 + row];
                        acc[k][ti][ti][reg] += q * q;
                    }
                }
    }

    // ---- 2) epilogue: ping-pong pairs of planes through P01 / P23 ----
    const int tx = t & 15;
    const int ty = t >> 4;
    const size_t NN = (size_t)NDIM * NDIM;
    float* obase = out + (size_t)n0 * NDIM + m0;

    auto MIX2 = [&](int b0, float* Qa, float* Qb) {     // formulas verbatim R8
        float pa[KDIM], pb[KDIM];
        #pragma unroll
        for (int k = 0; k < KDIM; ++k) {
            pa[k] = pl[b0 * KDIM + k];
            pb[k] = pl[(b0 + 1) * KDIM + k];
        }
        #pragma unroll
        for (int ti = 0; ti < 2; ++ti)
            #pragma unroll
            for (int tj = 0; tj < 2; ++tj)
                #pragma unroll
                for (int reg = 0; reg < 4; ++reg) {
                    const int rl = wr * 32 + ti * 16 + l4 * 4 + reg;
                    const int cl = wc * 32 + tj * 16 + l15;
                    float va = 0.0f, vb = 0.0f;
                    #pragma unroll
                    for (int k = 0; k < KDIM; ++k) {
                        va += pa[k] * acc[k][ti][tj][reg];
                        vb += pb[k] * acc[k][ti][tj][reg];
                    }
                    Qa[rl * FROW + cl] = va;
                    Qb[rl * FROW + cl] = vb;
                }
    };
    auto STORE2 = [&](int b0, const float* Qa, const float* Qb) {
        #pragma unroll
        for (int q = 0; q < 4; ++q) {
            const int row = ty + 16 * q;
            const f32x4 wa = *(const f32x4*)&Qa[row * FROW + tx * 4];
            const f32x4 wb = *(const f32x4*)&Qb[row * FROW + tx * 4];
            *(f32x4*)(obase + (size_t)b0 * NN
                            + (size_t)row * NDIM + tx * 4) = wa;
            *(f32x4*)(obase + (size_t)(b0 + 1) * NN
                            + (size_t)row * NDIM + tx * 4) = wb;
        }
    };
    auto BAR = [&]() {
        asm volatile("s_waitcnt lgkmcnt(0)" ::: "memory");  // my LDS ops done
        __builtin_amdgcn_s_barrier();                        // everyone's done
        __builtin_amdgcn_sched_barrier(0);
    };

    MIX2(0, P0, P1);          // pair 0 -> P01
    BAR();
    #pragma unroll 1
    for (int pp = 0; pp < 16; pp += 2) {
        MIX2(2 * (pp + 1), P2, P3);          // scatter pair pp+1 (always <16)
        STORE2(2 * pp, P0, P1);              // store pair pp
        BAR();                               // P23 ready; P01 reads done
        if (pp + 2 < 16) MIX2(2 * (pp + 2), P0, P1);
        STORE2(2 * (pp + 1), P2, P3);
        BAR();                               // P01 ready; P23 reads done
    }
}

extern "C" void kernel_launch(void* const* d_in, const int* in_sizes, int n_in,
                              void* d_out, int out_size, void* d_ws, size_t ws_size,
                              hipStream_t stream)
{
    const float* p  = (const float*)d_in[0];   // (B,K) = (32,8)
    const float* L  = (const float*)d_in[1];   // (K,N,F) = (8,2048,64)
    const float* sr = (const float*)d_in[2];   // (K,N)   = (8,2048)
    float* out = (float*)d_out;                // (B,N,N) = (32,2048,2048)

    dim3 grid(NDIM / TILE, NDIM / TILE);       // 32 x 32 = 1024 blocks
    hipLaunchKernelGGL(rfm_fused_mfma, grid, dim3(256), 0, stream,
                       p, L, sr, out);
}